// Round 18
// baseline (188.843 us; speedup 1.0000x reference)
//
#include <hip/hip_runtime.h>
#include <math.h>

#define B_    4
#define S_    2048
#define IN_   256
#define H_    128
#define M_    128
#define NROWS (B_ * S_)     // 8192
#define RPB   32            // rows per block -> 256 blocks = 1 per CU
#define GRP   4             // rows per pipeline group
#define NGRP  8
#define TPB   512           // 8 waves: 0-3 producers, 4-7 consumers
#define XPAD  260
#define C0STRIDE 130        // padded LDS row stride for c0 (floats)
#define C0BYTES  (128 * C0STRIDE * 4)   // 66560

typedef float f4_t __attribute__((ext_vector_type(4)));

// Wave-specialized pipeline, R12 schedule, with c0 fully staged in LDS:
// consumer steady-state = {LDS reads + VALU + PLAIN f4 store} — zero global
// loads, exactly the fillBuffer configuration that measures 6.5+ TB/s.
// RPB=32/grid=256 -> one resident block per CU, 8-group pipeline, ramp paid once.
__global__ __launch_bounds__(TPB) void xlstm_pipe(
    const float* __restrict__ x,
    const float* __restrict__ c0,
    const float* __restrict__ n0,
    const float* __restrict__ w_q, const float* __restrict__ b_q,
    const float* __restrict__ w_k, const float* __restrict__ b_k,
    const float* __restrict__ w_v, const float* __restrict__ b_v,
    const float* __restrict__ w_i, const float* __restrict__ b_i,
    const float* __restrict__ w_f, const float* __restrict__ b_f,
    const float* __restrict__ w_o, const float* __restrict__ b_o,
    float* __restrict__ out_h,
    float* __restrict__ out_c,
    float* __restrict__ out_n)
{
    __shared__ float xs[RPB][XPAD];        // 33.3 KB
    __shared__ float bq[2][GRP][M_];       // 2 KB x 8 = 16 KB
    __shared__ float bk[2][GRP][M_];
    __shared__ float bv[2][GRP][M_];
    __shared__ float bo[2][GRP][M_];
    __shared__ float itf[RPB][2];
    __shared__ float scalb[2][GRP][2];
    extern __shared__ float c0s[];         // [128][C0STRIDE] dynamic, 65 KB

    const int t    = threadIdx.x;
    const int row0 = blockIdx.x * RPB;
    const bool prod = (t < 256);

    // ---- stage x (32 rows) and c0 (into padded LDS), all 512 threads ----
    for (int p4 = t; p4 < RPB * IN_ / 4; p4 += TPB) {
        int p = p4 * 4;
        float4 v = *(const float4*)(x + (size_t)row0 * IN_ + p);
        *(float4*)&xs[p >> 8][p & 255] = v;
    }
    for (int i = t; i < 4096; i += TPB) {              // 4096 f4 = 64 KB
        f4_t v = *(const f4_t*)(c0 + (size_t)i * 4);
        int m = i >> 5, j4 = i & 31;
        *(f4_t*)&c0s[m * C0STRIDE + j4 * 4] = v;
    }
    __syncthreads();

    // ---- gates for all 32 rows: ALL 512 threads (32 rows x 16 segs) ----
    {
        const int gr = t >> 4, gseg = t & 15;
        const float* xrow = &xs[gr][gseg * 16];
        float pi = 0.f, pf = 0.f;
        #pragma unroll
        for (int u = 0; u < 4; ++u) {
            float4 xv  = *(const float4*)(xrow + u * 4);
            float4 wiv = *(const float4*)(w_i + gseg * 16 + u * 4);
            float4 wfv = *(const float4*)(w_f + gseg * 16 + u * 4);
            pi = fmaf(xv.x,wiv.x, fmaf(xv.y,wiv.y, fmaf(xv.z,wiv.z, fmaf(xv.w,wiv.w, pi))));
            pf = fmaf(xv.x,wfv.x, fmaf(xv.y,wfv.y, fmaf(xv.z,wfv.z, fmaf(xv.w,wfv.w, pf))));
        }
        #pragma unroll
        for (int mm = 1; mm < 16; mm <<= 1) { pi += __shfl_xor(pi, mm); pf += __shfl_xor(pf, mm); }
        if (gseg == 0) {
            itf[gr][0] = __expf(pi + b_i[0]);
            itf[gr][1] = 1.f / (1.f + __expf(-(pf + b_f[0])));
        }
    }
    __syncthreads();

    // producer mapping: 4 cols x 1 matrix x 2 rows, full k
    const int cg  = t & 31;
    const int mat = (t >> 5) & 3;          // 0=q 1=k 2=v 3=o
    const int rh  = (t >> 7) & 1;
    const int c4  = cg * 4;
    const int col = t & 127;
    const float* W    = (mat==0)? w_q : (mat==1)? w_k : (mat==2)? w_v : w_o;
    const float* BIAS = (mat==0)? b_q : (mat==1)? b_k : (mat==2)? b_v : b_o;
    const f4_t bias4 = prod ? *(const f4_t*)(BIAS + c4) : (f4_t){0,0,0,0};
    const float kscale = 0.08838834764831843f;   // 1/sqrt(128)

    // consumer mapping
    const int ct   = t & 255;
    const int base = ct * 4;
    const int jj   = base & 127;

    float c0qA = 0.f, c0qB = 0.f;          // carried group->next-stage

    #pragma unroll 1
    for (int s = 0; s <= NGRP; ++s) {
        // ================= sub-stage A =================
        if (prod) {
            if (s > 0) {
                // h, n for group s-1 (uses scal/c0q from previous subB)
                const int b = (s - 1) & 1;
                #pragma unroll
                for (int rr = 0; rr < 2; ++rr) {
                    const int lrow = rh * 2 + rr;
                    const int row  = (s - 1) * GRP + lrow;
                    const size_t grow = (size_t)(row0 + row);
                    const float iv = itf[row][0], fv = itf[row][1];
                    out_n[grow * M_ + col] = fmaf(fv, n0[col], iv * bk[b][lrow][col]);
                    const float kq  = scalb[b][lrow][0];
                    const float n0q = scalb[b][lrow][1];
                    const float nq = fmaf(fv, n0q, iv * kq);
                    const float denom = fmaxf(fabsf(nq), 1.f);
                    const float c0q = rr ? c0qB : c0qA;
                    const float ht = fmaf(fv, c0q, iv * bv[b][lrow][col] * kq) / denom;
                    out_h[grow * H_ + col] = bo[b][lrow][col] * ht;
                }
            }
            if (s < NGRP) {
                // GEMM group s -> buf[s&1]
                const int b  = s & 1;
                const int r0 = s * GRP + rh * 2;
                f4_t acc0 = (f4_t){0.f,0.f,0.f,0.f};
                f4_t acc1 = (f4_t){0.f,0.f,0.f,0.f};
                #pragma unroll 4
                for (int it = 0; it < 64; ++it) {
                    const int k0 = it * 4;
                    const float* wp = W + (size_t)k0 * H_ + c4;
                    f4_t w0 = *(const f4_t*)(wp);
                    f4_t w1 = *(const f4_t*)(wp + H_);
                    f4_t w2 = *(const f4_t*)(wp + 2 * H_);
                    f4_t w3 = *(const f4_t*)(wp + 3 * H_);
                    f4_t xv0 = *(const f4_t*)&xs[r0][k0];
                    f4_t xv1 = *(const f4_t*)&xs[r0 + 1][k0];
                    acc0 += xv0.x*w0 + xv0.y*w1 + xv0.z*w2 + xv0.w*w3;
                    acc1 += xv1.x*w0 + xv1.y*w1 + xv1.z*w2 + xv1.w*w3;
                }
                acc0 += bias4; acc1 += bias4;
                if (mat == 1) { acc0 *= kscale; acc1 *= kscale; }
                if (mat == 3) {
                    acc0.x = 1.f/(1.f+__expf(-acc0.x)); acc0.y = 1.f/(1.f+__expf(-acc0.y));
                    acc0.z = 1.f/(1.f+__expf(-acc0.z)); acc0.w = 1.f/(1.f+__expf(-acc0.w));
                    acc1.x = 1.f/(1.f+__expf(-acc1.x)); acc1.y = 1.f/(1.f+__expf(-acc1.y));
                    acc1.z = 1.f/(1.f+__expf(-acc1.z)); acc1.w = 1.f/(1.f+__expf(-acc1.w));
                }
                float (*DST)[M_] = (mat==0)? bq[b] : (mat==1)? bk[b] : (mat==2)? bv[b] : bo[b];
                const int lr = rh * 2;
                *(f4_t*)&DST[lr][c4]     = acc0;
                *(f4_t*)&DST[lr + 1][c4] = acc1;
            }
        } else if (s > 0) {
            // consumers subA: rows 0,1 of group s-1 — LDS-only reads, plain stores
            const int b     = (s - 1) & 1;
            const int gbase = (s - 1) * GRP;
            f4_t k40 = *(const f4_t*)&bk[b][0][jj];
            f4_t k41 = *(const f4_t*)&bk[b][1][jj];
            const float if0 = itf[gbase][0],     ff0 = itf[gbase][1];
            const float if1 = itf[gbase + 1][0], ff1 = itf[gbase + 1][1];
            float* o0 = out_c + (size_t)(row0 + gbase)     * (M_ * M_);
            float* o1 = out_c + (size_t)(row0 + gbase + 1) * (M_ * M_);
            #pragma unroll 2
            for (int ch = 0; ch < 16; ++ch) {
                const int p = (ch << 10) + base;
                const int m = p >> 7;
                f4_t c0v = *(const f4_t*)&c0s[m * C0STRIDE + (p & 127)];
                f4_t oa = ff0 * c0v + (if0 * bv[b][0][m]) * k40;
                f4_t ob = ff1 * c0v + (if1 * bv[b][1][m]) * k41;
                *(f4_t*)(o0 + p) = oa;
                *(f4_t*)(o1 + p) = ob;
            }
        }
        __syncthreads();
        // ================= sub-stage B =================
        if (prod) {
            if (s < NGRP) {
                const int b  = s & 1;
                const int lr = rh * 2;
                // c0q for group s (from LDS c0, padded stride)
                float a0 = 0.f, a1 = 0.f;
                const float* c0row = c0s + (size_t)col * C0STRIDE;
                #pragma unroll 2
                for (int j4 = 0; j4 < M_; j4 += 4) {
                    f4_t w4 = *(const f4_t*)(c0row + j4);
                    f4_t qa = *(const f4_t*)&bq[b][lr][j4];
                    f4_t qb = *(const f4_t*)&bq[b][lr + 1][j4];
                    a0 = fmaf(w4.x,qa.x, fmaf(w4.y,qa.y, fmaf(w4.z,qa.z, fmaf(w4.w,qa.w, a0))));
                    a1 = fmaf(w4.x,qb.x, fmaf(w4.y,qb.y, fmaf(w4.z,qb.z, fmaf(w4.w,qb.w, a1))));
                }
                c0qA = a0; c0qB = a1;
                // scal (kq, n0q): producer wave wv handles local row wv
                const int wv = t >> 6;     // 0..3
                const int l  = t & 63;
                const float ka  = bk[b][wv][l], kb2 = bk[b][wv][l + 64];
                const float qa2 = bq[b][wv][l], qb2 = bq[b][wv][l + 64];
                float pkq = fmaf(ka, qa2, kb2 * qb2);
                float pnq = fmaf(n0[l], qa2, n0[l + 64] * qb2);
                #pragma unroll
                for (int mm = 1; mm < 64; mm <<= 1) { pkq += __shfl_xor(pkq, mm); pnq += __shfl_xor(pnq, mm); }
                if (l == 0) { scalb[b][wv][0] = pkq; scalb[b][wv][1] = pnq; }
            }
        } else if (s > 0) {
            // consumers subB: rows 2,3 of group s-1 — LDS-only reads, plain stores
            const int b     = (s - 1) & 1;
            const int gbase = (s - 1) * GRP;
            f4_t k42 = *(const f4_t*)&bk[b][2][jj];
            f4_t k43 = *(const f4_t*)&bk[b][3][jj];
            const float if2 = itf[gbase + 2][0], ff2 = itf[gbase + 2][1];
            const float if3 = itf[gbase + 3][0], ff3 = itf[gbase + 3][1];
            float* o2 = out_c + (size_t)(row0 + gbase + 2) * (M_ * M_);
            float* o3 = out_c + (size_t)(row0 + gbase + 3) * (M_ * M_);
            #pragma unroll 2
            for (int ch = 0; ch < 16; ++ch) {
                const int p = (ch << 10) + base;
                const int m = p >> 7;
                f4_t c0v = *(const f4_t*)&c0s[m * C0STRIDE + (p & 127)];
                f4_t oa = ff2 * c0v + (if2 * bv[b][2][m]) * k42;
                f4_t ob = ff3 * c0v + (if3 * bv[b][3][m]) * k43;
                *(f4_t*)(o2 + p) = oa;
                *(f4_t*)(o3 + p) = ob;
            }
        }
        __syncthreads();
    }
}

extern "C" void kernel_launch(void* const* d_in, const int* in_sizes, int n_in,
                              void* d_out, int out_size, void* d_ws, size_t ws_size,
                              hipStream_t stream) {
    const float* x   = (const float*)d_in[0];
    const float* c0  = (const float*)d_in[1];
    const float* n0  = (const float*)d_in[2];
    const float* w_q = (const float*)d_in[3];  const float* b_q = (const float*)d_in[4];
    const float* w_k = (const float*)d_in[5];  const float* b_k = (const float*)d_in[6];
    const float* w_v = (const float*)d_in[7];  const float* b_v = (const float*)d_in[8];
    const float* w_i = (const float*)d_in[9];  const float* b_i = (const float*)d_in[10];
    const float* w_f = (const float*)d_in[11]; const float* b_f = (const float*)d_in[12];
    const float* w_o = (const float*)d_in[13]; const float* b_o = (const float*)d_in[14];

    float* out   = (float*)d_out;
    float* out_h = out;
    float* out_c = out + (size_t)NROWS * H_;
    float* out_n = out_c + (size_t)NROWS * M_ * M_;

    // allow >64KB dynamic LDS (needed for the 65KB padded c0 stage)
    (void)hipFuncSetAttribute((const void*)xlstm_pipe,
                              hipFuncAttributeMaxDynamicSharedMemorySize,
                              C0BYTES);

    hipLaunchKernelGGL(xlstm_pipe, dim3(NROWS / RPB), dim3(TPB), C0BYTES, stream,
                       x, c0, n0, w_q, b_q, w_k, b_k, w_v, b_v,
                       w_i, b_i, w_f, b_f, w_o, b_o,
                       out_h, out_c, out_n);
}

// Round 19
// 140.604 us; speedup vs baseline: 1.3431x; 1.3431x over previous
//
#include <hip/hip_runtime.h>
#include <math.h>

#define B_    4
#define S_    2048
#define IN_   256
#define H_    128
#define M_    128
#define NROWS (B_ * S_)     // 8192
#define RPB   16            // rows per block
#define GRP   4             // rows per pipeline group
#define NGRP  4
#define TPB   512           // 8 waves: 0-3 producers, 4-7 consumers
#define XPAD  260

typedef float f4_t __attribute__((ext_vector_type(4)));

// R12 schedule, byte-identical except: consumer loops use a 1-chunk rotating
// c0 prefetch — the load for chunk ch+1 issues BEFORE the stores of chunk ch,
// so (vmcnt FIFO) the load completes at vmcnt(2) without draining the younger
// stores, hiding c0 latency under the store stream.
__global__ __launch_bounds__(TPB) void xlstm_pipe(
    const float* __restrict__ x,
    const float* __restrict__ c0,
    const float* __restrict__ n0,
    const float* __restrict__ w_q, const float* __restrict__ b_q,
    const float* __restrict__ w_k, const float* __restrict__ b_k,
    const float* __restrict__ w_v, const float* __restrict__ b_v,
    const float* __restrict__ w_i, const float* __restrict__ b_i,
    const float* __restrict__ w_f, const float* __restrict__ b_f,
    const float* __restrict__ w_o, const float* __restrict__ b_o,
    float* __restrict__ out_h,
    float* __restrict__ out_c,
    float* __restrict__ out_n)
{
    __shared__ float xs[RPB][XPAD];        // 16.6 KB
    __shared__ float bq[2][GRP][M_];       // 2 KB x 8 = 16 KB
    __shared__ float bk[2][GRP][M_];
    __shared__ float bv[2][GRP][M_];
    __shared__ float bo[2][GRP][M_];
    __shared__ float itf[RPB][2];
    __shared__ float scalb[2][GRP][2];

    const int t    = threadIdx.x;
    const int row0 = blockIdx.x * RPB;
    const bool prod = (t < 256);

    // ---- stage x (all 512 threads) ----
    for (int p4 = t; p4 < RPB * IN_ / 4; p4 += TPB) {
        int p = p4 * 4;
        float4 v = *(const float4*)(x + (size_t)row0 * IN_ + p);
        *(float4*)&xs[p >> 8][p & 255] = v;
    }
    __syncthreads();

    // producer mapping: 4 cols x 1 matrix x 2 rows, full k
    const int cg  = t & 31;
    const int mat = (t >> 5) & 3;          // 0=q 1=k 2=v 3=o
    const int rh  = (t >> 7) & 1;
    const int c4  = cg * 4;
    const int col = t & 127;
    const float* W    = (mat==0)? w_q : (mat==1)? w_k : (mat==2)? w_v : w_o;
    const float* BIAS = (mat==0)? b_q : (mat==1)? b_k : (mat==2)? b_v : b_o;
    const f4_t bias4 = *(const f4_t*)(BIAS + c4);
    const float kscale = 0.08838834764831843f;   // 1/sqrt(128)

    // consumer mapping
    const int ct   = t & 255;
    const int base = ct * 4;
    const int jj   = base & 127;

    float c0qA = 0.f, c0qB = 0.f;          // carried group->next-stage

    #pragma unroll 1
    for (int s = 0; s <= NGRP; ++s) {
        // ================= sub-stage A =================
        if (prod) {
            if (s == 0) {
                // gates for all 16 rows (wave-parallel)
                const int gr = t >> 4, gseg = t & 15;
                const float* xrow = &xs[gr][gseg * 16];
                float pi = 0.f, pf = 0.f;
                #pragma unroll
                for (int u = 0; u < 4; ++u) {
                    float4 xv  = *(const float4*)(xrow + u * 4);
                    float4 wiv = *(const float4*)(w_i + gseg * 16 + u * 4);
                    float4 wfv = *(const float4*)(w_f + gseg * 16 + u * 4);
                    pi = fmaf(xv.x,wiv.x, fmaf(xv.y,wiv.y, fmaf(xv.z,wiv.z, fmaf(xv.w,wiv.w, pi))));
                    pf = fmaf(xv.x,wfv.x, fmaf(xv.y,wfv.y, fmaf(xv.z,wfv.z, fmaf(xv.w,wfv.w, pf))));
                }
                #pragma unroll
                for (int mm = 1; mm < 16; mm <<= 1) { pi += __shfl_xor(pi, mm); pf += __shfl_xor(pf, mm); }
                if (gseg == 0) {
                    itf[gr][0] = __expf(pi + b_i[0]);
                    itf[gr][1] = 1.f / (1.f + __expf(-(pf + b_f[0])));
                }
            }
            if (s > 0) {
                // h, n for group s-1 (uses scal/c0q from previous subB)
                const int b = (s - 1) & 1;
                #pragma unroll
                for (int rr = 0; rr < 2; ++rr) {
                    const int lrow = rh * 2 + rr;
                    const int row  = (s - 1) * GRP + lrow;
                    const size_t grow = (size_t)(row0 + row);
                    const float iv = itf[row][0], fv = itf[row][1];
                    out_n[grow * M_ + col] = fmaf(fv, n0[col], iv * bk[b][lrow][col]);
                    const float kq  = scalb[b][lrow][0];
                    const float n0q = scalb[b][lrow][1];
                    const float nq = fmaf(fv, n0q, iv * kq);
                    const float denom = fmaxf(fabsf(nq), 1.f);
                    const float c0q = rr ? c0qB : c0qA;
                    const float ht = fmaf(fv, c0q, iv * bv[b][lrow][col] * kq) / denom;
                    out_h[grow * H_ + col] = bo[b][lrow][col] * ht;
                }
            }
            if (s < NGRP) {
                // GEMM group s -> buf[s&1]
                const int b  = s & 1;
                const int r0 = s * GRP + rh * 2;
                f4_t acc0 = (f4_t){0.f,0.f,0.f,0.f};
                f4_t acc1 = (f4_t){0.f,0.f,0.f,0.f};
                #pragma unroll 4
                for (int it = 0; it < 64; ++it) {
                    const int k0 = it * 4;
                    const float* wp = W + (size_t)k0 * H_ + c4;
                    f4_t w0 = *(const f4_t*)(wp);
                    f4_t w1 = *(const f4_t*)(wp + H_);
                    f4_t w2 = *(const f4_t*)(wp + 2 * H_);
                    f4_t w3 = *(const f4_t*)(wp + 3 * H_);
                    f4_t xv0 = *(const f4_t*)&xs[r0][k0];
                    f4_t xv1 = *(const f4_t*)&xs[r0 + 1][k0];
                    acc0 += xv0.x*w0 + xv0.y*w1 + xv0.z*w2 + xv0.w*w3;
                    acc1 += xv1.x*w0 + xv1.y*w1 + xv1.z*w2 + xv1.w*w3;
                }
                acc0 += bias4; acc1 += bias4;
                if (mat == 1) { acc0 *= kscale; acc1 *= kscale; }
                if (mat == 3) {
                    acc0.x = 1.f/(1.f+__expf(-acc0.x)); acc0.y = 1.f/(1.f+__expf(-acc0.y));
                    acc0.z = 1.f/(1.f+__expf(-acc0.z)); acc0.w = 1.f/(1.f+__expf(-acc0.w));
                    acc1.x = 1.f/(1.f+__expf(-acc1.x)); acc1.y = 1.f/(1.f+__expf(-acc1.y));
                    acc1.z = 1.f/(1.f+__expf(-acc1.z)); acc1.w = 1.f/(1.f+__expf(-acc1.w));
                }
                float (*DST)[M_] = (mat==0)? bq[b] : (mat==1)? bk[b] : (mat==2)? bv[b] : bo[b];
                const int lr = rh * 2;
                *(f4_t*)&DST[lr][c4]     = acc0;
                *(f4_t*)&DST[lr + 1][c4] = acc1;
            }
        } else if (s > 0) {
            // consumers: rows 0,1 of group s-1 — rotating c0 prefetch
            const int b     = (s - 1) & 1;
            const int gbase = (s - 1) * GRP;
            f4_t k40 = *(const f4_t*)&bk[b][0][jj];
            f4_t k41 = *(const f4_t*)&bk[b][1][jj];
            const float if0 = itf[gbase][0],     ff0 = itf[gbase][1];
            const float if1 = itf[gbase + 1][0], ff1 = itf[gbase + 1][1];
            float* o0 = out_c + (size_t)(row0 + gbase)     * (M_ * M_);
            float* o1 = out_c + (size_t)(row0 + gbase + 1) * (M_ * M_);
            f4_t c0v = *(const f4_t*)(c0 + base);          // prefetch ch=0
            #pragma unroll 1
            for (int ch = 0; ch < 16; ++ch) {
                const int p = (ch << 10) + base;
                f4_t c0n;
                if (ch < 15) c0n = *(const f4_t*)(c0 + p + 1024);  // prefetch ch+1
                const int m = p >> 7;
                f4_t oa = ff0 * c0v + (if0 * bv[b][0][m]) * k40;
                f4_t ob = ff1 * c0v + (if1 * bv[b][1][m]) * k41;
                __builtin_nontemporal_store(oa, (f4_t*)(o0 + p));
                __builtin_nontemporal_store(ob, (f4_t*)(o1 + p));
                c0v = c0n;
            }
        }
        __syncthreads();
        // ================= sub-stage B =================
        if (prod) {
            if (s < NGRP) {
                const int b  = s & 1;
                const int lr = rh * 2;
                // c0q for group s (into carried registers)
                float a0 = 0.f, a1 = 0.f;
                const float* c0row = c0 + (size_t)col * M_;
                #pragma unroll 2
                for (int j4 = 0; j4 < M_; j4 += 4) {
                    f4_t w4 = *(const f4_t*)(c0row + j4);
                    f4_t qa = *(const f4_t*)&bq[b][lr][j4];
                    f4_t qb = *(const f4_t*)&bq[b][lr + 1][j4];
                    a0 = fmaf(w4.x,qa.x, fmaf(w4.y,qa.y, fmaf(w4.z,qa.z, fmaf(w4.w,qa.w, a0))));
                    a1 = fmaf(w4.x,qb.x, fmaf(w4.y,qb.y, fmaf(w4.z,qb.z, fmaf(w4.w,qb.w, a1))));
                }
                c0qA = a0; c0qB = a1;
                // scal (kq, n0q): producer wave wv handles local row wv
                const int wv = t >> 6;     // 0..3
                const int l  = t & 63;
                const float ka  = bk[b][wv][l], kb2 = bk[b][wv][l + 64];
                const float qa2 = bq[b][wv][l], qb2 = bq[b][wv][l + 64];
                float pkq = fmaf(ka, qa2, kb2 * qb2);
                float pnq = fmaf(n0[l], qa2, n0[l + 64] * qb2);
                #pragma unroll
                for (int mm = 1; mm < 64; mm <<= 1) { pkq += __shfl_xor(pkq, mm); pnq += __shfl_xor(pnq, mm); }
                if (l == 0) { scalb[b][wv][0] = pkq; scalb[b][wv][1] = pnq; }
            }
        } else if (s > 0) {
            // consumers: rows 2,3 of group s-1 — rotating c0 prefetch
            const int b     = (s - 1) & 1;
            const int gbase = (s - 1) * GRP;
            f4_t k42 = *(const f4_t*)&bk[b][2][jj];
            f4_t k43 = *(const f4_t*)&bk[b][3][jj];
            const float if2 = itf[gbase + 2][0], ff2 = itf[gbase + 2][1];
            const float if3 = itf[gbase + 3][0], ff3 = itf[gbase + 3][1];
            float* o2 = out_c + (size_t)(row0 + gbase + 2) * (M_ * M_);
            float* o3 = out_c + (size_t)(row0 + gbase + 3) * (M_ * M_);
            f4_t c0v = *(const f4_t*)(c0 + base);          // prefetch ch=0
            #pragma unroll 1
            for (int ch = 0; ch < 16; ++ch) {
                const int p = (ch << 10) + base;
                f4_t c0n;
                if (ch < 15) c0n = *(const f4_t*)(c0 + p + 1024);  // prefetch ch+1
                const int m = p >> 7;
                f4_t oa = ff2 * c0v + (if2 * bv[b][2][m]) * k42;
                f4_t ob = ff3 * c0v + (if3 * bv[b][3][m]) * k43;
                __builtin_nontemporal_store(oa, (f4_t*)(o2 + p));
                __builtin_nontemporal_store(ob, (f4_t*)(o3 + p));
                c0v = c0n;
            }
        }
        __syncthreads();
    }
}

extern "C" void kernel_launch(void* const* d_in, const int* in_sizes, int n_in,
                              void* d_out, int out_size, void* d_ws, size_t ws_size,
                              hipStream_t stream) {
    const float* x   = (const float*)d_in[0];
    const float* c0  = (const float*)d_in[1];
    const float* n0  = (const float*)d_in[2];
    const float* w_q = (const float*)d_in[3];  const float* b_q = (const float*)d_in[4];
    const float* w_k = (const float*)d_in[5];  const float* b_k = (const float*)d_in[6];
    const float* w_v = (const float*)d_in[7];  const float* b_v = (const float*)d_in[8];
    const float* w_i = (const float*)d_in[9];  const float* b_i = (const float*)d_in[10];
    const float* w_f = (const float*)d_in[11]; const float* b_f = (const float*)d_in[12];
    const float* w_o = (const float*)d_in[13]; const float* b_o = (const float*)d_in[14];

    float* out   = (float*)d_out;
    float* out_h = out;
    float* out_c = out + (size_t)NROWS * H_;
    float* out_n = out_c + (size_t)NROWS * M_ * M_;

    hipLaunchKernelGGL(xlstm_pipe, dim3(NROWS / RPB), dim3(TPB), 0, stream,
                       x, c0, n0, w_q, b_q, w_k, b_k, w_v, b_v,
                       w_i, b_i, w_f, b_f, w_o, b_o,
                       out_h, out_c, out_n);
}

// Round 20
// 138.238 us; speedup vs baseline: 1.3661x; 1.0171x over previous
//
#include <hip/hip_runtime.h>
#include <math.h>

#define B_    4
#define S_    2048
#define IN_   256
#define H_    128
#define M_    128
#define NROWS (B_ * S_)     // 8192
#define RPB   16            // rows per block
#define GRP   4             // rows per pipeline group
#define NGRP  4
#define TPB   512           // 8 waves: 0-3 producers, 4-7 consumers
#define XPAD  260

typedef float f4_t __attribute__((ext_vector_type(4)));

// FINAL: wave-specialized pipelined kernel (R12, measured best 138.3 us).
// Per block (16 rows): producers (waves 0-3) run proj GEMM per 4-row group
// into double-buffered LDS, then c0q/scal, then h,n; consumers (waves 4-7)
// stream c for the previous group with nt stores. vmcnt is per-wave, so
// consumer store drains never block producer weight loads. nt stores are
// load-bearing (plain stores thrash L2: -35 us). Two barriers per stage.
__global__ __launch_bounds__(TPB) void xlstm_pipe(
    const float* __restrict__ x,
    const float* __restrict__ c0,
    const float* __restrict__ n0,
    const float* __restrict__ w_q, const float* __restrict__ b_q,
    const float* __restrict__ w_k, const float* __restrict__ b_k,
    const float* __restrict__ w_v, const float* __restrict__ b_v,
    const float* __restrict__ w_i, const float* __restrict__ b_i,
    const float* __restrict__ w_f, const float* __restrict__ b_f,
    const float* __restrict__ w_o, const float* __restrict__ b_o,
    float* __restrict__ out_h,
    float* __restrict__ out_c,
    float* __restrict__ out_n)
{
    __shared__ float xs[RPB][XPAD];        // 16.6 KB
    __shared__ float bq[2][GRP][M_];       // 2 KB x 8 = 16 KB
    __shared__ float bk[2][GRP][M_];
    __shared__ float bv[2][GRP][M_];
    __shared__ float bo[2][GRP][M_];
    __shared__ float itf[RPB][2];
    __shared__ float scalb[2][GRP][2];

    const int t    = threadIdx.x;
    const int row0 = blockIdx.x * RPB;
    const bool prod = (t < 256);

    // ---- stage x (all 512 threads) ----
    for (int p4 = t; p4 < RPB * IN_ / 4; p4 += TPB) {
        int p = p4 * 4;
        float4 v = *(const float4*)(x + (size_t)row0 * IN_ + p);
        *(float4*)&xs[p >> 8][p & 255] = v;
    }
    __syncthreads();

    // producer mapping: 4 cols x 1 matrix x 2 rows, full k
    const int cg  = t & 31;
    const int mat = (t >> 5) & 3;          // 0=q 1=k 2=v 3=o
    const int rh  = (t >> 7) & 1;
    const int c4  = cg * 4;
    const int col = t & 127;
    const float* W    = (mat==0)? w_q : (mat==1)? w_k : (mat==2)? w_v : w_o;
    const float* BIAS = (mat==0)? b_q : (mat==1)? b_k : (mat==2)? b_v : b_o;
    const f4_t bias4 = *(const f4_t*)(BIAS + c4);
    const float kscale = 0.08838834764831843f;   // 1/sqrt(128)

    // consumer mapping
    const int ct   = t & 255;
    const int base = ct * 4;
    const int jj   = base & 127;

    float c0qA = 0.f, c0qB = 0.f;          // carried group->next-stage

    #pragma unroll 1
    for (int s = 0; s <= NGRP; ++s) {
        // ================= sub-stage A =================
        if (prod) {
            if (s == 0) {
                // gates for all 16 rows (wave-parallel)
                const int gr = t >> 4, gseg = t & 15;
                const float* xrow = &xs[gr][gseg * 16];
                float pi = 0.f, pf = 0.f;
                #pragma unroll
                for (int u = 0; u < 4; ++u) {
                    float4 xv  = *(const float4*)(xrow + u * 4);
                    float4 wiv = *(const float4*)(w_i + gseg * 16 + u * 4);
                    float4 wfv = *(const float4*)(w_f + gseg * 16 + u * 4);
                    pi = fmaf(xv.x,wiv.x, fmaf(xv.y,wiv.y, fmaf(xv.z,wiv.z, fmaf(xv.w,wiv.w, pi))));
                    pf = fmaf(xv.x,wfv.x, fmaf(xv.y,wfv.y, fmaf(xv.z,wfv.z, fmaf(xv.w,wfv.w, pf))));
                }
                #pragma unroll
                for (int mm = 1; mm < 16; mm <<= 1) { pi += __shfl_xor(pi, mm); pf += __shfl_xor(pf, mm); }
                if (gseg == 0) {
                    itf[gr][0] = __expf(pi + b_i[0]);
                    itf[gr][1] = 1.f / (1.f + __expf(-(pf + b_f[0])));
                }
            }
            if (s > 0) {
                // h, n for group s-1 (uses scal/c0q from previous subB)
                const int b = (s - 1) & 1;
                #pragma unroll
                for (int rr = 0; rr < 2; ++rr) {
                    const int lrow = rh * 2 + rr;
                    const int row  = (s - 1) * GRP + lrow;
                    const size_t grow = (size_t)(row0 + row);
                    const float iv = itf[row][0], fv = itf[row][1];
                    out_n[grow * M_ + col] = fmaf(fv, n0[col], iv * bk[b][lrow][col]);
                    const float kq  = scalb[b][lrow][0];
                    const float n0q = scalb[b][lrow][1];
                    const float nq = fmaf(fv, n0q, iv * kq);
                    const float denom = fmaxf(fabsf(nq), 1.f);
                    const float c0q = rr ? c0qB : c0qA;
                    const float ht = fmaf(fv, c0q, iv * bv[b][lrow][col] * kq) / denom;
                    out_h[grow * H_ + col] = bo[b][lrow][col] * ht;
                }
            }
            if (s < NGRP) {
                // GEMM group s -> buf[s&1]
                const int b  = s & 1;
                const int r0 = s * GRP + rh * 2;
                f4_t acc0 = (f4_t){0.f,0.f,0.f,0.f};
                f4_t acc1 = (f4_t){0.f,0.f,0.f,0.f};
                #pragma unroll 4
                for (int it = 0; it < 64; ++it) {
                    const int k0 = it * 4;
                    const float* wp = W + (size_t)k0 * H_ + c4;
                    f4_t w0 = *(const f4_t*)(wp);
                    f4_t w1 = *(const f4_t*)(wp + H_);
                    f4_t w2 = *(const f4_t*)(wp + 2 * H_);
                    f4_t w3 = *(const f4_t*)(wp + 3 * H_);
                    f4_t xv0 = *(const f4_t*)&xs[r0][k0];
                    f4_t xv1 = *(const f4_t*)&xs[r0 + 1][k0];
                    acc0 += xv0.x*w0 + xv0.y*w1 + xv0.z*w2 + xv0.w*w3;
                    acc1 += xv1.x*w0 + xv1.y*w1 + xv1.z*w2 + xv1.w*w3;
                }
                acc0 += bias4; acc1 += bias4;
                if (mat == 1) { acc0 *= kscale; acc1 *= kscale; }
                if (mat == 3) {
                    acc0.x = 1.f/(1.f+__expf(-acc0.x)); acc0.y = 1.f/(1.f+__expf(-acc0.y));
                    acc0.z = 1.f/(1.f+__expf(-acc0.z)); acc0.w = 1.f/(1.f+__expf(-acc0.w));
                    acc1.x = 1.f/(1.f+__expf(-acc1.x)); acc1.y = 1.f/(1.f+__expf(-acc1.y));
                    acc1.z = 1.f/(1.f+__expf(-acc1.z)); acc1.w = 1.f/(1.f+__expf(-acc1.w));
                }
                float (*DST)[M_] = (mat==0)? bq[b] : (mat==1)? bk[b] : (mat==2)? bv[b] : bo[b];
                const int lr = rh * 2;
                *(f4_t*)&DST[lr][c4]     = acc0;
                *(f4_t*)&DST[lr + 1][c4] = acc1;
            }
        } else if (s > 0) {
            // consumers: stream local rows 0,1 of group s-1
            const int b     = (s - 1) & 1;
            const int gbase = (s - 1) * GRP;
            #pragma unroll 2
            for (int ch = 0; ch < 16; ++ch) {
                const int p = (ch << 10) + base;
                const int m = p >> 7;
                f4_t c0v = *(const f4_t*)(c0 + p);
                #pragma unroll
                for (int r = 0; r < 2; ++r) {
                    const int row = gbase + r;
                    f4_t k4 = *(const f4_t*)&bk[b][r][jj];
                    float sf = itf[row][0] * bv[b][r][m];
                    f4_t o4 = itf[row][1] * c0v + sf * k4;
                    __builtin_nontemporal_store(o4,
                        (f4_t*)(out_c + (size_t)(row0 + row) * (M_ * M_) + p));
                }
            }
        }
        __syncthreads();
        // ================= sub-stage B =================
        if (prod) {
            if (s < NGRP) {
                const int b  = s & 1;
                const int lr = rh * 2;
                // c0q for group s (into carried registers)
                float a0 = 0.f, a1 = 0.f;
                const float* c0row = c0 + (size_t)col * M_;
                #pragma unroll 2
                for (int j4 = 0; j4 < M_; j4 += 4) {
                    f4_t w4 = *(const f4_t*)(c0row + j4);
                    f4_t qa = *(const f4_t*)&bq[b][lr][j4];
                    f4_t qb = *(const f4_t*)&bq[b][lr + 1][j4];
                    a0 = fmaf(w4.x,qa.x, fmaf(w4.y,qa.y, fmaf(w4.z,qa.z, fmaf(w4.w,qa.w, a0))));
                    a1 = fmaf(w4.x,qb.x, fmaf(w4.y,qb.y, fmaf(w4.z,qb.z, fmaf(w4.w,qb.w, a1))));
                }
                c0qA = a0; c0qB = a1;
                // scal (kq, n0q): producer wave wv handles local row wv
                const int wv = t >> 6;     // 0..3
                const int l  = t & 63;
                const float ka  = bk[b][wv][l], kb2 = bk[b][wv][l + 64];
                const float qa2 = bq[b][wv][l], qb2 = bq[b][wv][l + 64];
                float pkq = fmaf(ka, qa2, kb2 * qb2);
                float pnq = fmaf(n0[l], qa2, n0[l + 64] * qb2);
                #pragma unroll
                for (int mm = 1; mm < 64; mm <<= 1) { pkq += __shfl_xor(pkq, mm); pnq += __shfl_xor(pnq, mm); }
                if (l == 0) { scalb[b][wv][0] = pkq; scalb[b][wv][1] = pnq; }
            }
        } else if (s > 0) {
            // consumers: stream local rows 2,3 of group s-1
            const int b     = (s - 1) & 1;
            const int gbase = (s - 1) * GRP;
            #pragma unroll 2
            for (int ch = 0; ch < 16; ++ch) {
                const int p = (ch << 10) + base;
                const int m = p >> 7;
                f4_t c0v = *(const f4_t*)(c0 + p);
                #pragma unroll
                for (int r = 2; r < 4; ++r) {
                    const int row = gbase + r;
                    f4_t k4 = *(const f4_t*)&bk[b][r][jj];
                    float sf = itf[row][0] * bv[b][r][m];
                    f4_t o4 = itf[row][1] * c0v + sf * k4;
                    __builtin_nontemporal_store(o4,
                        (f4_t*)(out_c + (size_t)(row0 + row) * (M_ * M_) + p));
                }
            }
        }
        __syncthreads();
    }
}

extern "C" void kernel_launch(void* const* d_in, const int* in_sizes, int n_in,
                              void* d_out, int out_size, void* d_ws, size_t ws_size,
                              hipStream_t stream) {
    const float* x   = (const float*)d_in[0];
    const float* c0  = (const float*)d_in[1];
    const float* n0  = (const float*)d_in[2];
    const float* w_q = (const float*)d_in[3];  const float* b_q = (const float*)d_in[4];
    const float* w_k = (const float*)d_in[5];  const float* b_k = (const float*)d_in[6];
    const float* w_v = (const float*)d_in[7];  const float* b_v = (const float*)d_in[8];
    const float* w_i = (const float*)d_in[9];  const float* b_i = (const float*)d_in[10];
    const float* w_f = (const float*)d_in[11]; const float* b_f = (const float*)d_in[12];
    const float* w_o = (const float*)d_in[13]; const float* b_o = (const float*)d_in[14];

    float* out   = (float*)d_out;
    float* out_h = out;
    float* out_c = out + (size_t)NROWS * H_;
    float* out_n = out_c + (size_t)NROWS * M_ * M_;

    hipLaunchKernelGGL(xlstm_pipe, dim3(NROWS / RPB), dim3(TPB), 0, stream,
                       x, c0, n0, w_q, b_q, w_k, b_k, w_v, b_v,
                       w_i, b_i, w_f, b_f, w_o, b_o,
                       out_h, out_c, out_n);
}